// Round 7
// baseline (20.727 us; speedup 1.0000x reference)
//
#include <hip/hip_runtime.h>

#define H 200
#define NP 64
#define NIMG 24
#define NB 8
#define NPIX (H*H)
#define GSTEP (2.0f/199.0f)
#define SPI 20          // strip-halves per image (10 y-strips x 2 x-halves)
#define NWORK (NIMG*SPI)

typedef __fp16 h2 __attribute__((ext_vector_type(2)));

__device__ __forceinline__ float fdot2f(unsigned int a, unsigned int b, float c) {
  h2 ha = __builtin_bit_cast(h2, a);
  h2 hb = __builtin_bit_cast(h2, b);
#if __has_builtin(__builtin_amdgcn_fdot2)
  return __builtin_amdgcn_fdot2(ha, hb, c, false);
#else
  return c + (float)ha.x * (float)hb.x + (float)ha.y * (float)hb.y;
#endif
}

__device__ __forceinline__ unsigned int pk2(float lo, float hi) {
#if __has_builtin(__builtin_amdgcn_cvt_pkrtz)
  h2 h = __builtin_amdgcn_cvt_pkrtz(lo, hi);
  return __builtin_bit_cast(unsigned int, h);
#else
  h2 h; h.x = (__fp16)lo; h.y = (__fp16)hi;
  return __builtin_bit_cast(unsigned int, h);
#endif
}

// K1: one block per (img, y-strip of 20 rows, x-half of 100 cols). 256 thr.
// f32: Sy (full-y recompute), colsum/cinv, ex table, score fold.
// f16 dot2: mask GEMM (pairs over n), score t-GEMM (pairs over y, M staged to LDS).
__global__ __launch_bounds__(256) void prs_main(
    const float* __restrict__ cam,   // (8,3,2,3)
    const float* __restrict__ cloud, // (8,64,3)
    const float* __restrict__ mt,    // (8,3,200,200)
    const float* __restrict__ blur,  // (8,64)
    const float* __restrict__ b3,    // (8,3)
    const float* __restrict__ b2,    // (8,3,2)
    float* __restrict__ out,
    float* __restrict__ ws_msum,     // [NWORK]
    float* __restrict__ ws_scr)      // [NWORK][64]
{
  __shared__ float ex[NP*100];          // [n][x] f32          25600 B
  __shared__ float eys[20*NP];          // [y][n] f32           5120 B
  __shared__ unsigned int exp2_[32*100];// [n2][x] f16-pair    12800 B
  __shared__ unsigned int eyp2[32*20];  // [n2][y] f16-pair     2560 B
  __shared__ unsigned int eyy[NP*12];   // [n][y2] f16-pair     3072 B (10 used)
  __shared__ unsigned int Mp[100*12];   // [x][y2] f16-pair     4800 B (10 used)
  __shared__ float cinv[100];
  __shared__ float Sy[NP];
  __shared__ float ptx[NP], pty[NP], i2s[NP];
  __shared__ float red[256];            // Syp, then msum reduce

  const int tid = threadIdx.x;
  const int blk = blockIdx.x;
  const int img = blk / SPI;
  const int rem = blk - img * SPI;
  const int strip = rem >> 1;
  const int xh = rem & 1;
  const int b = img / 3;
  const int c = img - 3 * b;
  const int ys0 = strip * 20;
  const int xb = xh * 100;

  // ---- A1: point params ----
  if (tid < NP) {
    int n = tid;
    float p0 = cloud[(b*NP + n)*3 + 0] + b3[b*3 + 0];
    float p1 = cloud[(b*NP + n)*3 + 1] + b3[b*3 + 1];
    float p2 = cloud[(b*NP + n)*3 + 2] + b3[b*3 + 2];
    const float* cc = cam + ((b*3 + c)*2)*3;
    float px = cc[0]*p0 + cc[1]*p1 + cc[2]*p2 - b2[(b*3 + c)*2 + 0];
    float py = cc[3]*p0 + cc[4]*p1 + cc[5]*p2 - b2[(b*3 + c)*2 + 1];
    ptx[n] = fminf(fmaxf(px * 0.01f, -1.0f), 1.0f);
    pty[n] = fminf(fmaxf(py * 0.01f, -1.0f), 1.0f);
    float s = blur[b*NP + n];
    i2s[n] = 1.0f / (2.0f * s * s);
  }
  __syncthreads();

  // ---- A2: eys (strip), ex (x-half), Syp (full-y, into red) ----
  for (int e = tid; e < 20*NP; e += 256) {
    int y = e >> 6, n = e & 63;
    float d = (-1.0f + (ys0 + y)*GSTEP) - pty[n];
    eys[y*NP + n] = __expf(-d*d*i2s[n]);
  }
  for (int e = tid; e < NP*100; e += 256) {
    int n = e / 100, x = e - n*100;
    float d = (-1.0f + (xb + x)*GSTEP) - ptx[n];
    ex[n*100 + x] = __expf(-d*d*i2s[n]);
  }
  {
    int n = tid & 63, g = tid >> 6;
    float pyv = pty[n], iv = i2s[n];
    float s = 0.0f;
    for (int y = g*50; y < g*50 + 50; ++y) {
      float d = (-1.0f + y*GSTEP) - pyv;
      s += __expf(-d*d*iv);
    }
    red[g*NP + n] = s;
  }
  __syncthreads();

  // ---- A3: f16 packs + M staging + Sy reduce ----
  for (int e = tid; e < 3200; e += 256) {           // exp2_[n2][x]
    int n2 = e / 100, x = e - n2*100;
    exp2_[n2*100 + x] = pk2(ex[(2*n2)*100 + x], ex[(2*n2+1)*100 + x]);
  }
  for (int e = tid; e < 640; e += 256) {            // eyp2[n2][y]
    int n2 = e / 20, y = e - n2*20;
    eyp2[n2*20 + y] = pk2(eys[y*NP + 2*n2], eys[y*NP + 2*n2 + 1]);
  }
  for (int e = tid; e < 640; e += 256) {            // eyy[n][y2]
    int n = e / 10, y2 = e - n*10;
    eyy[n*12 + y2] = pk2(eys[(2*y2)*NP + n], eys[(2*y2+1)*NP + n]);
  }
  for (int e = tid; e < 1000; e += 256) {           // Mp[x][y2]
    int y2 = e / 100, x = e - y2*100;
    const float* mb = mt + img*NPIX + (ys0 + 2*y2)*H + xb + x;
    Mp[x*12 + y2] = pk2(mb[0], mb[H]);
  }
  if (tid < NP)
    Sy[tid] = red[tid] + red[NP + tid] + red[2*NP + tid] + red[3*NP + tid];
  __syncthreads();

  // ---- A4: cinv (all f32) ----
  if (tid < 100) {
    float s = 0.0f;
    for (int n = 0; n < NP; ++n) s += ex[n*100 + tid] * Sy[n];
    cinv[tid] = 1.0f / fmaxf(s, 1e-8f);
  }
  __syncthreads();

  // ---- B: wave 0-1 mask GEMM, wave 2-3 score GEMM ----
  float msl = 0.0f;
  if (tid < 128) {
    if (tid < 125) {
      int yg = tid / 25;
      int xg = tid - yg*25;
      int x0 = xg*4, y0 = yg*4;
      float acc[4][4];
      #pragma unroll
      for (int i = 0; i < 4; ++i)
        #pragma unroll
        for (int j = 0; j < 4; ++j) acc[i][j] = 0.0f;
      for (int n2 = 0; n2 < 32; ++n2) {
        uint4 eyv = *(uint4*)&eyp2[n2*20 + y0];
        uint4 exv = *(uint4*)&exp2_[n2*100 + x0];
        acc[0][0]=fdot2f(eyv.x,exv.x,acc[0][0]); acc[0][1]=fdot2f(eyv.x,exv.y,acc[0][1]);
        acc[0][2]=fdot2f(eyv.x,exv.z,acc[0][2]); acc[0][3]=fdot2f(eyv.x,exv.w,acc[0][3]);
        acc[1][0]=fdot2f(eyv.y,exv.x,acc[1][0]); acc[1][1]=fdot2f(eyv.y,exv.y,acc[1][1]);
        acc[1][2]=fdot2f(eyv.y,exv.z,acc[1][2]); acc[1][3]=fdot2f(eyv.y,exv.w,acc[1][3]);
        acc[2][0]=fdot2f(eyv.z,exv.x,acc[2][0]); acc[2][1]=fdot2f(eyv.z,exv.y,acc[2][1]);
        acc[2][2]=fdot2f(eyv.z,exv.z,acc[2][2]); acc[2][3]=fdot2f(eyv.z,exv.w,acc[2][3]);
        acc[3][0]=fdot2f(eyv.w,exv.x,acc[3][0]); acc[3][1]=fdot2f(eyv.w,exv.y,acc[3][1]);
        acc[3][2]=fdot2f(eyv.w,exv.z,acc[3][2]); acc[3][3]=fdot2f(eyv.w,exv.w,acc[3][3]);
      }
      float* ob = out + img*NPIX;
      #pragma unroll
      for (int i = 0; i < 4; ++i) {
        float4 v;
        v.x = fminf(acc[i][0], 1.0f);
        v.y = fminf(acc[i][1], 1.0f);
        v.z = fminf(acc[i][2], 1.0f);
        v.w = fminf(acc[i][3], 1.0f);
        msl += v.x + v.y + v.z + v.w;
        *(float4*)&ob[(ys0 + y0 + i)*H + xb + x0] = v;
      }
    }
  } else {
    int st = tid - 128;
    int ng = st >> 3;
    int xt = st & 7;
    int n0 = ng * 4;
    uint4 ea[4], eb4[4]; uint2 ec[4];
    #pragma unroll
    for (int i = 0; i < 4; ++i) {
      const unsigned int* p = &eyy[(n0 + i)*12];
      ea[i]  = *(const uint4*)p;
      eb4[i] = *(const uint4*)(p + 4);
      ec[i]  = *(const uint2*)(p + 8);
    }
    float sacc[4] = {0.0f, 0.0f, 0.0f, 0.0f};
    for (int x = xt; x < 100; x += 8) {
      const unsigned int* q = &Mp[x*12];
      uint4 ma = *(const uint4*)q;
      uint4 mb = *(const uint4*)(q + 4);
      uint2 mc = *(const uint2*)(q + 8);
      float cvx = cinv[x];
      #pragma unroll
      for (int i = 0; i < 4; ++i) {
        float t = 0.0f;
        t = fdot2f(ea[i].x, ma.x, t);  t = fdot2f(ea[i].y, ma.y, t);
        t = fdot2f(ea[i].z, ma.z, t);  t = fdot2f(ea[i].w, ma.w, t);
        t = fdot2f(eb4[i].x, mb.x, t); t = fdot2f(eb4[i].y, mb.y, t);
        t = fdot2f(eb4[i].z, mb.z, t); t = fdot2f(eb4[i].w, mb.w, t);
        t = fdot2f(ec[i].x, mc.x, t);  t = fdot2f(ec[i].y, mc.y, t);
        sacc[i] += t * ex[(n0 + i)*100 + x] * cvx;
      }
    }
    #pragma unroll
    for (int off = 4; off > 0; off >>= 1) {
      #pragma unroll
      for (int i = 0; i < 4; ++i) sacc[i] += __shfl_down(sacc[i], off, 8);
    }
    if (xt == 0) {
      #pragma unroll
      for (int i = 0; i < 4; ++i) ws_scr[blk*NP + n0 + i] = sacc[i];
    }
  }

  // block reduce mask partial sum
  red[tid] = msl;
  __syncthreads();
  #pragma unroll
  for (int s = 128; s > 0; s >>= 1) {
    if (tid < s) red[tid] += red[tid + s];
    __syncthreads();
  }
  if (tid == 0) ws_msum[blk] = red[0];
}

// K2: blocks 0..479 normalize one 20x100 region; blocks 480..487 reduce scores.
__global__ __launch_bounds__(256) void prs_finish(
    float* __restrict__ out,
    const float* __restrict__ ws_msum,
    const float* __restrict__ ws_scr)
{
  const int blk = blockIdx.x;
  const int tid = threadIdx.x;
  if (blk < NWORK) {
    const int img = blk / SPI;
    const int rem = blk - img * SPI;
    const int strip = rem >> 1;
    const int xh = rem & 1;
    __shared__ float invs;
    if (tid == 0) {
      float s = 0.0f;
      for (int i = 0; i < SPI; ++i) s += ws_msum[img*SPI + i];
      invs = 1.0f / fmaxf(s, 1e-8f);
    }
    __syncthreads();
    const float inv = invs;
    for (int q = tid; q < 500; q += 256) {   // 20 rows x 25 float4
      int ry = q / 25;
      int rx = q - ry * 25;
      float* p = out + img*NPIX + (strip*20 + ry)*H + xh*100 + rx*4;
      float4 v = *(float4*)p;
      v.x *= inv; v.y *= inv; v.z *= inv; v.w *= inv;
      *(float4*)p = v;
    }
  } else {
    const int bb = blk - NWORK;
    if (tid < NP) {
      float s = 0.0f;
      for (int cc = 0; cc < 3; ++cc)
        for (int sh = 0; sh < SPI; ++sh)
          s += ws_scr[((bb*3 + cc)*SPI + sh)*NP + tid];
      out[NIMG*NPIX + bb*NP + tid] = s * (1.0f/3.0f);
    }
  }
}

extern "C" void kernel_launch(void* const* d_in, const int* in_sizes, int n_in,
                              void* d_out, int out_size, void* d_ws, size_t ws_size,
                              hipStream_t stream) {
  const float* cam   = (const float*)d_in[0];
  const float* cloud = (const float*)d_in[1];
  const float* mt    = (const float*)d_in[2];
  const float* blur  = (const float*)d_in[3];
  const float* b3    = (const float*)d_in[4];
  const float* b2    = (const float*)d_in[5];
  float* out = (float*)d_out;

  float* ws_msum = (float*)d_ws;        // 480 floats (pad to 512)
  float* ws_scr  = ws_msum + 512;       // 480*64 floats

  prs_main<<<NWORK, 256, 0, stream>>>(cam, cloud, mt, blur, b3, b2,
                                      out, ws_msum, ws_scr);
  prs_finish<<<NWORK + NB, 256, 0, stream>>>(out, ws_msum, ws_scr);
}